// Round 12
// baseline (482.998 us; speedup 1.0000x reference)
//
#include <hip/hip_runtime.h>
#include <hip/hip_cooperative_groups.h>

namespace cg = cooperative_groups;

#define N_NODES 100000
#define N_EDGES 1000000
#define DIM 64
#define N_GRAPHS 1024
#define OUT_DIM 16
#define NLAYERS 4

#define BN 64        // nodes per block in layer kernel
#define NB 1563      // ceil(N_NODES/BN)
#define BLOCK 256    // 4 waves
#define NWAVES 4
#define RPW 16       // rows per wave = 2 merged 8-row groups
#define SA 65        // LDS row stride: 65%32==1 -> conflict-free column access
#define NGRP 12500   // N_NODES/8 wave-groups

// ---- bucket sort params ----
#define NBKT2 391            // ceil(N_NODES/256) buckets of 256 dst nodes
#define BCH 4096             // edges per pass-1 block
#define NBLK1 245            // ceil(N_EDGES/BCH)
#define SLACK 1800           // per-bucket region slack: 256*7 pad + 8 (align eats <=7)
#define EPB (N_EDGES + NBKT2 * SLACK)
#define SENTSRC N_NODES      // sentinel src -> zero bf16 row

typedef unsigned short ushort8_t __attribute__((ext_vector_type(8)));
typedef unsigned short ushort4_t __attribute__((ext_vector_type(4)));
typedef __bf16 bf16x8v __attribute__((ext_vector_type(8)));
typedef float f32x4v __attribute__((ext_vector_type(4)));

union bfu { ushort8_t u; bf16x8v b; };

__device__ __forceinline__ float b2f(unsigned short u) {
    union { unsigned int i; float f; } c;
    c.i = ((unsigned int)u) << 16;
    return c.f;
}
__device__ __forceinline__ unsigned short f2b(float f) {  // RNE
    union { float f; unsigned int i; } c;
    c.f = f;
    return (unsigned short)((c.i + 0x7FFFu + ((c.i >> 16) & 1u)) >> 16);
}

// block-wide exclusive scan of one int per thread (256 threads); tmp = 4+ ints LDS
__device__ __forceinline__ int blk_excl_scan_256(int v, int tid, int* tmp) {
    int lane = tid & 63, w = tid >> 6;
    int inc = v;
#pragma unroll
    for (int o = 1; o < 64; o <<= 1) { int u = __shfl_up(inc, o, 64); if (lane >= o) inc += u; }
    __syncthreads();              // protect tmp from any previous use
    if (lane == 63) tmp[w] = inc;
    __syncthreads();
    if (tid == 0) { int r = 0; for (int i = 0; i < 4; ++i) { int t2 = tmp[i]; tmp[i] = r; r += t2; } }
    __syncthreads();
    return inc - v + tmp[w];
}

// ---------------- fused CSR build: prep -> colscan -> scanb2 -> p1 -> p2 ----------------
// R12: the 5 build kernels collapsed into ONE cooperative kernel with
// grid.sync() between phases. R11 showed per-block inner work is NOT the
// build's cost (int4/BCH changes ~ null) -> the cost is launch/drain
// boundaries (~5-10us each). Grid = 391 blocks x 256 thr; LDS = p1's 30.3KB
// (p2 aliases p1's arrays); co-residency 391/256 < 2 blocks/CU, LDS allows 5.
// NO global atomic reservations (R8/R9 lesson: they cost 11us).
__global__ __launch_bounds__(256) void build_kernel(
    const int* __restrict__ src, const int* __restrict__ dst,
    const float4* __restrict__ x,
    int* __restrict__ hblk, ushort4* __restrict__ bf0, ushort4* __restrict__ bf1,
    float* __restrict__ g, const float* __restrict__ Wrel,
    const float* __restrict__ Wroot, unsigned short* __restrict__ wT,
    int* __restrict__ gsize, int* __restrict__ Abase, int* __restrict__ Bbase,
    int* __restrict__ edgesA, int* __restrict__ edgesB,
    int* __restrict__ rpS, int* __restrict__ wend8) {
    cg::grid_group grid = cg::this_grid();
    __shared__ int h[NBKT2], start[NBKT2], curb[NBKT2], resv[NBKT2], tmp[4];
    __shared__ int sortedv[BCH];
    __shared__ unsigned short sortedb[BCH];
    const int tid = threadIdx.x, bid = blockIdx.x;
    const int GSTR = NBKT2 * 256;   // grid stride

    // ---- P0: prep (histogram for bid<NBLK1; streaming work for all) ----
    if (bid < NBLK1) {
        for (int i = tid; i < NBKT2; i += 256) h[i] = 0;
        __syncthreads();
        int e0 = bid * BCH;
        int nloc = min(BCH, N_EDGES - e0);          // 4096 or 576: both /4
        const int4* __restrict__ dst4 = reinterpret_cast<const int4*>(dst + e0);
        int n4l = nloc >> 2;
        for (int i = tid; i < n4l; i += 256) {
            int4 d4 = dst4[i];
            atomicAdd(&h[d4.x >> 8], 1); atomicAdd(&h[d4.y >> 8], 1);
            atomicAdd(&h[d4.z >> 8], 1); atomicAdd(&h[d4.w >> 8], 1);
        }
    }
    {   // tobf (independent)
        const int n4 = N_NODES * (DIM / 4);
        for (int i = bid * 256 + tid; i < n4; i += GSTR) {
            float4 v = x[i];
            ushort4 b;
            b.x = f2b(v.x); b.y = f2b(v.y); b.z = f2b(v.z); b.w = f2b(v.w);
            bf0[i] = b;
        }
        // zero g (pool is fused into last layer)
        const int g4 = N_GRAPHS * (DIM / 4);
        float4 z4 = make_float4(0.f, 0.f, 0.f, 0.f);
        for (int i = bid * 256 + tid; i < g4; i += GSTR)
            reinterpret_cast<float4*>(g)[i] = z4;
        // transposed bf16 weight concat: wT[((l*64+n)*128)+k]
        const int wtot = NLAYERS * DIM * 2 * DIM;   // 32768
        for (int i = bid * 256 + tid; i < wtot; i += GSTR) {
            int k = i & 127, n = (i >> 7) & 63, l = i >> 13;
            float v = (k < DIM) ? Wrel[l * DIM * DIM + k * DIM + n]
                                : Wroot[l * DIM * DIM + (k - DIM) * DIM + n];
            wT[i] = f2b(v);
        }
        // zero sentinel rows of both bf buffers
        if (bid == 0 && tid < 32) {
            ushort4 z; z.x = 0; z.y = 0; z.z = 0; z.w = 0;
            if (tid < 16) bf0[(size_t)N_NODES * 16 + tid] = z;
            else          bf1[(size_t)N_NODES * 16 + (tid - 16)] = z;
        }
    }
    if (bid < NBLK1) {
        __syncthreads();
        for (int i = tid; i < NBKT2; i += 256) hblk[(size_t)bid * NBKT2 + i] = h[i];
    }
    grid.sync();

    // ---- P1: column scan (block = bucket): scan the NBLK1 per-block counts ----
    {
        int c = bid;
        int i0 = 2 * tid, i1 = 2 * tid + 1;
        int a = (i0 < NBLK1) ? hblk[(size_t)i0 * NBKT2 + c] : 0;
        int b = (i1 < NBLK1) ? hblk[(size_t)i1 * NBKT2 + c] : 0;
        int s = blk_excl_scan_256(a + b, tid, tmp);
        if (i0 < NBLK1) hblk[(size_t)i0 * NBKT2 + c] = s;
        if (i1 < NBLK1) hblk[(size_t)i1 * NBKT2 + c] = s + a;
        if (tid == 255) gsize[c] = s + a + b;   // column total
    }
    grid.sync();

    // ---- P2: scan bucket totals -> Abase, Bbase (block 0 only) ----
    // Bbase rounded to x8 ints (32B): every 8-edge row chunk is 32B-aligned.
    if (bid == 0) {
        int c0 = 2 * tid, c1 = 2 * tid + 1;
        int a = (c0 < NBKT2) ? gsize[c0] : 0;
        int b = (c1 < NBKT2) ? gsize[c1] : 0;
        int s = blk_excl_scan_256(a + b, tid, tmp);
        if (c0 < NBKT2) Abase[c0] = s;
        if (c1 < NBKT2) Abase[c1] = s + a;
        int a2 = (c0 < NBKT2) ? a + SLACK : 0;
        int b2 = (c1 < NBKT2) ? b + SLACK : 0;
        int s2 = blk_excl_scan_256(a2 + b2, tid, tmp);
        if (c0 < NBKT2) Bbase[c0] = (s2 + 7) & ~7;
        if (c1 < NBKT2) Bbase[c1] = (s2 + a2 + 7) & ~7;
    }
    grid.sync();

    // ---- P3: p1 bucket sort (bid < NBLK1) ----
    if (bid < NBLK1) {
        int e0 = bid * BCH;
        int nloc = min(BCH, N_EDGES - e0);
        for (int i = tid; i < NBKT2; i += 256) h[i] = 0;
        __syncthreads();
        int myc[16], myv[16];
        const int4* __restrict__ src4 = reinterpret_cast<const int4*>(src + e0);
        const int4* __restrict__ dst4 = reinterpret_cast<const int4*>(dst + e0);
        const int n4l = nloc >> 2;
#pragma unroll
        for (int k4 = 0; k4 < 4; ++k4) {
            int i4 = k4 * 256 + tid;
            if (i4 < n4l) {
                int4 d = dst4[i4];
                int4 s = src4[i4];
                myc[k4 * 4 + 0] = d.x >> 8; myv[k4 * 4 + 0] = ((d.x & 255) << 17) | s.x;
                myc[k4 * 4 + 1] = d.y >> 8; myv[k4 * 4 + 1] = ((d.y & 255) << 17) | s.y;
                myc[k4 * 4 + 2] = d.z >> 8; myv[k4 * 4 + 2] = ((d.z & 255) << 17) | s.z;
                myc[k4 * 4 + 3] = d.w >> 8; myv[k4 * 4 + 3] = ((d.w & 255) << 17) | s.w;
                atomicAdd(&h[myc[k4 * 4 + 0]], 1);
                atomicAdd(&h[myc[k4 * 4 + 1]], 1);
                atomicAdd(&h[myc[k4 * 4 + 2]], 1);
                atomicAdd(&h[myc[k4 * 4 + 3]], 1);
            } else {
#pragma unroll
                for (int j = 0; j < 4; ++j) myc[k4 * 4 + j] = -1;
            }
        }
        __syncthreads();
        {   // scan h -> start (2 elems/thread over 512 slots)
            int a = (2 * tid < NBKT2) ? h[2 * tid] : 0;
            int b = (2 * tid + 1 < NBKT2) ? h[2 * tid + 1] : 0;
            int s = blk_excl_scan_256(a + b, tid, tmp);
            if (2 * tid < NBKT2) start[2 * tid] = s;
            if (2 * tid + 1 < NBKT2) start[2 * tid + 1] = s + a;
        }
        __syncthreads();
        for (int i = tid; i < NBKT2; i += 256) curb[i] = start[i];
        __syncthreads();
#pragma unroll
        for (int k = 0; k < 16; ++k) if (myc[k] >= 0) {
            int r = atomicAdd(&curb[myc[k]], 1);
            sortedv[r] = myv[k];
            sortedb[r] = (unsigned short)myc[k];
        }
        __syncthreads();
        // reservation = precomputed block-prefix (colscan) -- no global atomics
        for (int i = tid; i < NBKT2; i += 256) resv[i] = hblk[(size_t)bid * NBKT2 + i];
        __syncthreads();
        for (int i = tid; i < nloc; i += 256) {                  // coalesced run writes
            int c = sortedb[i];
            edgesA[Abase[c] + resv[c] + (i - start[c])] = sortedv[i];
        }
    }
    grid.sync();

    // ---- P4: p2 per-bucket scatter (block = bucket); aliases p1's LDS ----
    // cnt->h, off->start, pend->curb, curx->resv
    {
        int b = bid;
        int nb0 = b * 256;
        int nn = min(256, N_NODES - nb0);
        int ne = gsize[b];
        int abase = Abase[b], bbase = Bbase[b];
        h[tid] = 0;
        __syncthreads();
        for (int i = tid; i < ne; i += 256) atomicAdd(&h[edgesA[abase + i] >> 17], 1);
        __syncthreads();
        int c = h[tid];
        int c8 = (tid < nn) ? ((c + 7) & ~7) : 0;
        int o = blk_excl_scan_256(c8, tid, tmp);
        start[tid] = o; curb[tid] = o + c8; resv[tid] = bbase + o;
        __syncthreads();
        int gc = nn >> 3;
        if (tid < gc) {
            rpS[(nb0 >> 3) + tid] = bbase + start[tid * 8];
            wend8[(nb0 >> 3) + tid] = bbase + curb[tid * 8 + 7];
        }
        for (int i = tid; i < ne; i += 256) {
            int p = edgesA[abase + i];
            int dl = p >> 17;
            int pos = atomicAdd(&resv[dl], 1);
            edgesB[pos] = ((dl & 7) << 17) | (p & 0x1FFFF);   // wave-local row | src
        }
        __syncthreads();
        if (tid < nn) {   // sentinel pads
            int pe = bbase + curb[tid];
            int sent = ((tid & 7) << 17) | SENTSRC;
            for (int pos = resv[tid]; pos < pe; ++pos) edgesB[pos] = sent;
        }
    }
}

// ---------------- fused GraphConv layer: bf16-only h (fp32 compute) ----------
// R7-proven Phase A (word lead 6 / gather lead 3 -- depth search concluded).
// R11 hoist: Phase B's own-row X fragments + brel loaded before Phase A.
template <bool LAST>
__global__ __launch_bounds__(BLOCK) void layer_kernel(
    const ushort8_t* __restrict__ hbf_in, ushort8_t* __restrict__ hbf_out,
    const unsigned short* __restrict__ wT, const float* __restrict__ brel,
    const int* __restrict__ rpS, const int* __restrict__ wend8,
    const int* __restrict__ edges8,
    const int* __restrict__ batch, float* __restrict__ g) {
    __shared__ float agg_s[BN * SA];   // 16.6 KB
    const int tid = threadIdx.x;
    const int lane = tid & 63;
    const int wave = __builtin_amdgcn_readfirstlane(tid >> 6);
    const int node0 = blockIdx.x * BN;
    const int nvalid = min(BN, N_NODES - node0);

#pragma unroll
    for (int r = 0; r < RPW; ++r) agg_s[(wave * RPW + r) * SA + lane] = 0.f;

    // hoisted Phase-B operands (independent of Phase A)
    const int ml = lane & 15;
    const int kq = lane >> 4;               // 0..3: k-subchunk
    const int mrow = wave * 16 + ml;        // A-operand row (node_local)
    const int nrow = min(node0 + mrow, N_NODES - 1);
    bfu af2, af3;
    af2.u = hbf_in[(size_t)nrow * 8 + kq];
    af3.u = hbf_in[(size_t)nrow * 8 + 4 + kq];
    float brv[4];
#pragma unroll
    for (int nt = 0; nt < 4; ++nt) brv[nt] = brel[nt * 16 + ml];

    // Phase A: one merged 16-row run per wave, lane=dim streaming, ring pipeline
    {
        const int gg = blockIdx.x * 8 + wave * 2;   // even; gg+1 in same bucket
        if (gg < NGRP) {
            const int eb    = rpS[gg];
            const int mid   = rpS[gg + 1];
            const int end   = wend8[gg + 1];
            const int nch   = (end - eb) >> 3;      // 8-edge chunks, each = one row
            const int midch = (mid - eb) >> 3;      // chunks >= midch -> rows 8..15
            const int m = lane & 15;                // this lane's dim quad: m*4..m*4+3
            const int q = lane >> 4;                // 0..3: handles edges q and q+4
            const ushort4_t* __restrict__ h4 = (const ushort4_t*)hbf_in;
            const int rbase = wave * RPW;

            float a0 = 0.f, a1 = 0.f, a2 = 0.f, a3 = 0.f;
            int cur = -1;

#define FLUSHROW(ROW) { \
    float f0 = a0, f1 = a1, f2 = a2, f3 = a3; \
    f0 += __shfl_xor(f0, 16, 64); f1 += __shfl_xor(f1, 16, 64); \
    f2 += __shfl_xor(f2, 16, 64); f3 += __shfl_xor(f3, 16, 64); \
    f0 += __shfl_xor(f0, 32, 64); f1 += __shfl_xor(f1, 32, 64); \
    f2 += __shfl_xor(f2, 32, 64); f3 += __shfl_xor(f3, 32, 64); \
    if (lane < 16) { \
        float* p = &agg_s[(rbase + (ROW)) * SA + m * 4]; \
        p[0] = f0; p[1] = f1; p[2] = f2; p[3] = f3; } }

// per-lane vector loads of the 2 edge words this lane consumes (vmcnt-counted)
#define LDW(WA, WB, CC) { \
    WA = edges8[eb + min((CC) * 8 + q,     lmax)]; \
    WB = edges8[eb + min((CC) * 8 + q + 4, lmax)]; }
// coalesced 8B gather of this lane's dim quad from rows WA, WB
#define GTH(VA_, VB_, WA, WB) { \
    VA_ = h4[(unsigned)(((WA) & 0x1FFFF) * 16 + m)]; \
    VB_ = h4[(unsigned)(((WB) & 0x1FFFF) * 16 + m)]; }

#define ACCV(VA_, VB_) { \
    a0 += b2f(VA_[0]); a1 += b2f(VA_[1]); a2 += b2f(VA_[2]); a3 += b2f(VA_[3]); \
    a0 += b2f(VB_[0]); a1 += b2f(VB_[1]); a2 += b2f(VB_[2]); a3 += b2f(VB_[3]); }

// one pipeline step: U_ static (ring indices compile-time), CC_ = chunk id
#define STEP(U_, CC_) { \
    LDW(wA[((U_) + 6) & 7], wB[((U_) + 6) & 7], (CC_) + 6) \
    GTH(VA[((U_) + 3) & 3], VB[((U_) + 3) & 3], wA[((U_) + 3) & 7], wB[((U_) + 3) & 7]) \
    const int row_ = (__builtin_amdgcn_readfirstlane(wA[(U_) & 7]) >> 17) \
                     + (((CC_) >= midch) ? 8 : 0); \
    if (row_ != cur) { \
        if (cur >= 0) FLUSHROW(cur) \
        cur = row_; \
        a0 = a1 = a2 = a3 = 0.f; \
    } \
    ACCV(VA[(U_) & 3], VB[(U_) & 3]) }

            if (nch > 0) {
                const int lmax = nch * 8 - 1;
                int wA[8], wB[8];            // ring: words of chunk c in slot c&7
                ushort4_t VA[4], VB[4];      // ring: gathered rows, slot c&3

                // prologue: words for chunks 0..5, gathers for chunks 0..2
#pragma unroll
                for (int p = 0; p < 6; ++p) LDW(wA[p], wB[p], p)
#pragma unroll
                for (int p = 0; p < 3; ++p) GTH(VA[p], VB[p], wA[p], wB[p])

                int c = 0;
                for (; c + 8 <= nch; c += 8) {   // main: static ring indices
#pragma unroll
                    for (int u = 0; u < 8; ++u) STEP(u, c + u)
                }
                if (c < nch) {                   // tail: guarded, still static
#pragma unroll
                    for (int u = 0; u < 8; ++u) {
                        if (c + u < nch) STEP(u, c + u)
                    }
                }
                if (cur >= 0) FLUSHROW(cur)
            }
#undef STEP
#undef ACCV
#undef LDW
#undef GTH
#undef FLUSHROW
        }
    }
    __syncthreads();

    // Phase B (MFMA): per wave, M-tile rows [wave*16,+16), all 4 N-tiles, K=128
    {
        bfu af[4];
        // kb 0,1: AGG (fp32 LDS -> bf16)
#pragma unroll
        for (int kb = 0; kb < 2; ++kb) {
            const float* ap = &agg_s[mrow * SA + kb * 32 + kq * 8];
#pragma unroll
            for (int j = 0; j < 8; ++j) af[kb].u[j] = f2b(ap[j]);
        }
        // kb 2,3: X own row (hoisted loads)
        af[2] = af2;
        af[3] = af3;

        f32x4v acc[4];
#pragma unroll
        for (int nt = 0; nt < 4; ++nt) {
            float bv = brv[nt];                 // D col = lane&15
            acc[nt][0] = bv; acc[nt][1] = bv; acc[nt][2] = bv; acc[nt][3] = bv;
        }
#pragma unroll
        for (int nt = 0; nt < 4; ++nt) {
            const ushort8_t* wrow =
                (const ushort8_t*)(wT + (size_t)(nt * 16 + ml) * 128);
#pragma unroll
            for (int kb = 0; kb < 4; ++kb) {
                bfu bfr; bfr.u = wrow[kb * 4 + kq];
                acc[nt] = __builtin_amdgcn_mfma_f32_16x16x32_bf16(
                    af[kb].b, bfr.b, acc[nt], 0, 0, 0);
            }
        }
        __syncthreads();   // all waves done reading agg_s
#pragma unroll
        for (int nt = 0; nt < 4; ++nt)
#pragma unroll
            for (int r = 0; r < 4; ++r)
                agg_s[(wave * 16 + kq * 4 + r) * SA + nt * 16 + ml] =
                    fmaxf(acc[nt][r], 0.f);
    }
    __syncthreads();

    if (LAST) {
        // fused global_add_pool: wave 0, lane = dim; batch is sorted
        if (wave == 0) {
            float acc = 0.f;
            int cur = batch[node0];
            for (int nl = 0; nl < nvalid; ++nl) {
                int bv = batch[node0 + nl];          // wave-uniform scalar
                float v = agg_s[nl * SA + lane];
                if (bv != cur) {
                    unsafeAtomicAdd(&g[(size_t)cur * DIM + lane], acc);
                    acc = 0.f; cur = bv;
                }
                acc += v;
            }
            unsafeAtomicAdd(&g[(size_t)cur * DIM + lane], acc);
        }
    } else {
        // coalesced bf16 store only (transpose via agg_s)
        for (int i = tid; i < nvalid * 8; i += BLOCK) {
            int nl = i >> 3, c8 = i & 7;
            const float* xp = &agg_s[nl * SA + c8 * 8];
            ushort8_t b;
#pragma unroll
            for (int j = 0; j < 8; ++j) b[j] = f2b(xp[j]);
            hbf_out[(size_t)(node0 + nl) * 8 + c8] = b;
        }
    }
}

// ---------------- classifier head: one wave per graph ----------------
__global__ __launch_bounds__(256) void head_kernel(
    const float* __restrict__ g, const float* __restrict__ W1, const float* __restrict__ b1,
    const float* __restrict__ W2, const float* __restrict__ b2, float* __restrict__ y) {
    __shared__ float ts[4][DIM];
    const int wave = threadIdx.x >> 6, lane = threadIdx.x & 63;
    const int gid = blockIdx.x * 4 + wave;          // 256*4 == N_GRAPHS exactly
    const float* __restrict__ grow = g + (size_t)gid * DIM;
    float t = b1[lane];
#pragma unroll 8
    for (int k = 0; k < DIM; ++k)
        t = fmaf(grow[k], W1[k * DIM + lane], t);   // grow[k] wave-uniform -> broadcast
    ts[wave][lane] = fmaxf(t, 0.f);
    __syncthreads();
    if (lane < OUT_DIM) {
        float acc = b2[lane];
#pragma unroll 8
        for (int d = 0; d < DIM; ++d)
            acc = fmaf(ts[wave][d], W2[d * OUT_DIM + lane], acc);
        y[(size_t)gid * OUT_DIM + lane] = acc;
    }
}

extern "C" void kernel_launch(void* const* d_in, const int* in_sizes, int n_in,
                              void* d_out, int out_size, void* d_ws, size_t ws_size,
                              hipStream_t stream) {
    const float* x     = (const float*)d_in[0];
    const int*   eidx  = (const int*)d_in[1];
    const int*   batch = (const int*)d_in[2];
    const float* Wrel  = (const float*)d_in[3];
    const float* brel  = (const float*)d_in[4];
    const float* Wroot = (const float*)d_in[5];
    const float* W1    = (const float*)d_in[6];
    const float* b1    = (const float*)d_in[7];
    const float* W2    = (const float*)d_in[8];
    const float* b2    = (const float*)d_in[9];
    float* y = (float*)d_out;

    char* ws = (char*)d_ws;
    const size_t BFBYTES = (size_t)(N_NODES + 1) * DIM * sizeof(unsigned short); // 12.8 MB + zero row
    size_t off = 0;
    ushort4* bf0 = (ushort4*)(ws + off); off += (BFBYTES + 255) / 256 * 256;
    ushort4* bf1 = (ushort4*)(ws + off); off += (BFBYTES + 255) / 256 * 256;
    int* rpS    = (int*)(ws + off); off += (size_t)NGRP * 4;
    int* wend8  = (int*)(ws + off); off += (size_t)NGRP * 4;
    int* gsize  = (int*)(ws + off); off += (size_t)NBKT2 * 4;
    int* Abase  = (int*)(ws + off); off += (size_t)NBKT2 * 4;
    int* Bbase  = (int*)(ws + off); off += (size_t)NBKT2 * 4;
    int* hblk   = (int*)(ws + off); off += (size_t)NBLK1 * NBKT2 * 4;  // 383 KB
    int* edgesA = (int*)(ws + off); off += (size_t)N_EDGES * 4;
    int* edgesB = (int*)(ws + off); off += (size_t)EPB * 4;
    float* g    = (float*)(ws + off); off += (size_t)N_GRAPHS * DIM * 4;
    unsigned short* wT = (unsigned short*)(ws + off);
    off += (size_t)NLAYERS * DIM * 2 * DIM * sizeof(unsigned short);   // 64 KB

    const int* src = eidx;
    const int* dst = eidx + N_EDGES;
    const float4* x4 = (const float4*)x;

    // fused CSR build (cooperative: 5 kernels -> 1, 4 grid.syncs)
    void* kargs[] = {
        (void*)&src, (void*)&dst, (void*)&x4,
        (void*)&hblk, (void*)&bf0, (void*)&bf1, (void*)&g,
        (void*)&Wrel, (void*)&Wroot, (void*)&wT,
        (void*)&gsize, (void*)&Abase, (void*)&Bbase,
        (void*)&edgesA, (void*)&edgesB, (void*)&rpS, (void*)&wend8
    };
    hipLaunchCooperativeKernel((void*)build_kernel, dim3(NBKT2), dim3(256),
                               kargs, 0, stream);

    // 4 GraphConv layers, bf16 ping-pong; last fuses pool
    layer_kernel<false><<<NB, BLOCK, 0, stream>>>((const ushort8_t*)bf0, (ushort8_t*)bf1,
        wT + 0 * DIM * 2 * DIM, brel + 0 * DIM, rpS, wend8, edgesB, batch, g);
    layer_kernel<false><<<NB, BLOCK, 0, stream>>>((const ushort8_t*)bf1, (ushort8_t*)bf0,
        wT + 1 * DIM * 2 * DIM, brel + 1 * DIM, rpS, wend8, edgesB, batch, g);
    layer_kernel<false><<<NB, BLOCK, 0, stream>>>((const ushort8_t*)bf0, (ushort8_t*)bf1,
        wT + 2 * DIM * 2 * DIM, brel + 2 * DIM, rpS, wend8, edgesB, batch, g);
    layer_kernel<true><<<NB, BLOCK, 0, stream>>>((const ushort8_t*)bf1, (ushort8_t*)bf0,
        wT + 3 * DIM * 2 * DIM, brel + 3 * DIM, rpS, wend8, edgesB, batch, g);

    // head
    head_kernel<<<N_GRAPHS / 4, 256, 0, stream>>>(g, W1, b1, W2, b2, y);
}

// Round 13
// 271.419 us; speedup vs baseline: 1.7795x; 1.7795x over previous
//
#include <hip/hip_runtime.h>

#define N_NODES 100000
#define N_EDGES 1000000
#define DIM 64
#define N_GRAPHS 1024
#define OUT_DIM 16
#define NLAYERS 4

#define BN 64        // nodes per block in layer kernel
#define NB 1563      // ceil(N_NODES/BN)
#define BLOCK 256    // 4 waves
#define NWAVES 4
#define RPW 16       // rows per wave = 2 merged 8-row groups
#define SA 65        // LDS row stride: 65%32==1 -> conflict-free column access
#define NGRP 12500   // N_NODES/8 wave-groups

// ---- bucket sort params ----
#define NBKT2 391            // ceil(N_NODES/256) buckets of 256 dst nodes
#define BCH 4096             // edges per pass-1 block
#define NBLK1 245            // ceil(N_EDGES/BCH)
#define SLACK 1800           // per-bucket region slack: 256*7 pad + 8 (align eats <=7)
#define EPB (N_EDGES + NBKT2 * SLACK)
#define SENTSRC N_NODES      // sentinel src -> zero bf16 row

typedef unsigned short ushort8_t __attribute__((ext_vector_type(8)));
typedef unsigned short ushort4_t __attribute__((ext_vector_type(4)));
typedef __bf16 bf16x8v __attribute__((ext_vector_type(8)));
typedef float f32x4v __attribute__((ext_vector_type(4)));

union bfu { ushort8_t u; bf16x8v b; };

__device__ __forceinline__ float b2f(unsigned short u) {
    union { unsigned int i; float f; } c;
    c.i = ((unsigned int)u) << 16;
    return c.f;
}
__device__ __forceinline__ unsigned short f2b(float f) {  // RNE
    union { float f; unsigned int i; } c;
    c.f = f;
    return (unsigned short)((c.i + 0x7FFFu + ((c.i >> 16) & 1u)) >> 16);
}

// block-wide exclusive scan of one int per thread (256 threads); tmp = 4+ ints LDS
__device__ __forceinline__ int blk_excl_scan_256(int v, int tid, int* tmp) {
    int lane = tid & 63, w = tid >> 6;
    int inc = v;
#pragma unroll
    for (int o = 1; o < 64; o <<= 1) { int u = __shfl_up(inc, o, 64); if (lane >= o) inc += u; }
    __syncthreads();              // protect tmp from any previous use
    if (lane == 63) tmp[w] = inc;
    __syncthreads();
    if (tid == 0) { int r = 0; for (int i = 0; i < 4; ++i) { int t2 = tmp[i]; tmp[i] = r; r += t2; } }
    __syncthreads();
    return inc - v + tmp[w];
}

// ---------------- prep: per-block histogram + tobf + zero g + sentinels + wT ----------------
// R10-proven structure (store counts, colscan later -- NO global atomics: R8/R9
// cost 11us; NO cooperative fusion: R12 grid.sync cost ~30-40us each).
__global__ __launch_bounds__(256) void prep_kernel(const int* __restrict__ dst,
                                                   int* __restrict__ hblk,
                                                   const float4* __restrict__ x,
                                                   ushort4* __restrict__ bf0,
                                                   ushort4* __restrict__ bf1,
                                                   float* __restrict__ g,
                                                   const float* __restrict__ Wrel,
                                                   const float* __restrict__ Wroot,
                                                   unsigned short* __restrict__ wT) {
    __shared__ int h[NBKT2];
    int tid = threadIdx.x;
    for (int i = tid; i < NBKT2; i += 256) h[i] = 0;
    __syncthreads();
    int e0 = blockIdx.x * BCH;
    int nloc = min(BCH, N_EDGES - e0);          // 4096 or 576: both /4
    const int4* __restrict__ dst4 = reinterpret_cast<const int4*>(dst + e0);
    int n4l = nloc >> 2;
    for (int i = tid; i < n4l; i += 256) {
        int4 d4 = dst4[i];
        atomicAdd(&h[d4.x >> 8], 1); atomicAdd(&h[d4.y >> 8], 1);
        atomicAdd(&h[d4.z >> 8], 1); atomicAdd(&h[d4.w >> 8], 1);
    }

    // tobf (independent)
    const int n4 = N_NODES * (DIM / 4);
    for (int i = blockIdx.x * 256 + tid; i < n4; i += NBLK1 * 256) {
        float4 v = x[i];
        ushort4 b;
        b.x = f2b(v.x); b.y = f2b(v.y); b.z = f2b(v.z); b.w = f2b(v.w);
        bf0[i] = b;
    }
    // zero g (independent; pool is fused into last layer)
    const int g4 = N_GRAPHS * (DIM / 4);
    float4 z4 = make_float4(0.f, 0.f, 0.f, 0.f);
    for (int i = blockIdx.x * 256 + tid; i < g4; i += NBLK1 * 256)
        reinterpret_cast<float4*>(g)[i] = z4;
    // transposed bf16 weight concat: wT[((l*64+n)*128)+k], k<64: Wrel[k][n], else Wroot[k-64][n]
    const int wtot = NLAYERS * DIM * 2 * DIM;   // 32768
    for (int i = blockIdx.x * 256 + tid; i < wtot; i += NBLK1 * 256) {
        int k = i & 127, n = (i >> 7) & 63, l = i >> 13;
        float v = (k < DIM) ? Wrel[l * DIM * DIM + k * DIM + n]
                            : Wroot[l * DIM * DIM + (k - DIM) * DIM + n];
        wT[i] = f2b(v);
    }
    // zero sentinel rows of both bf buffers
    if (blockIdx.x == 0 && tid < 32) {
        ushort4 z; z.x = 0; z.y = 0; z.z = 0; z.w = 0;
        if (tid < 16) bf0[(size_t)N_NODES * 16 + tid] = z;
        else          bf1[(size_t)N_NODES * 16 + (tid - 16)] = z;
    }
    __syncthreads();
    for (int i = tid; i < NBKT2; i += 256) hblk[(size_t)blockIdx.x * NBKT2 + i] = h[i];
}

// ---- column scan: one block per bucket, scan the 245 per-block counts ----
__global__ __launch_bounds__(256) void colscan_kernel(int* __restrict__ hblk,
                                                      int* __restrict__ gsize) {
    __shared__ int tmp[4];
    int c = blockIdx.x, t = threadIdx.x;
    int i0 = 2 * t, i1 = 2 * t + 1;
    int a = (i0 < NBLK1) ? hblk[(size_t)i0 * NBKT2 + c] : 0;
    int b = (i1 < NBLK1) ? hblk[(size_t)i1 * NBKT2 + c] : 0;
    int s = blk_excl_scan_256(a + b, t, tmp);
    if (i0 < NBLK1) hblk[(size_t)i0 * NBKT2 + c] = s;
    if (i1 < NBLK1) hblk[(size_t)i1 * NBKT2 + c] = s + a;
    if (t == 255) gsize[c] = s + a + b;   // column total
}

// tiny single block: scan 391 bucket totals -> Abase, Bbase
// Bbase rounded up to x8 ints (32B): every row-run chunk of 8 edges is then
// 32B-aligned (p2 pads runs to x8) -> chunk c of a run is one dst row.
__global__ __launch_bounds__(256) void scanb2_kernel(const int* __restrict__ gsize,
                                                     int* __restrict__ Abase,
                                                     int* __restrict__ Bbase) {
    __shared__ int tmp[4];
    int t = threadIdx.x;
    int c0 = 2 * t, c1 = 2 * t + 1;
    int a = (c0 < NBKT2) ? gsize[c0] : 0;
    int b = (c1 < NBKT2) ? gsize[c1] : 0;
    int s = blk_excl_scan_256(a + b, t, tmp);
    if (c0 < NBKT2) Abase[c0] = s;
    if (c1 < NBKT2) Abase[c1] = s + a;
    int a2 = (c0 < NBKT2) ? a + SLACK : 0;
    int b2 = (c1 < NBKT2) ? b + SLACK : 0;
    int s2 = blk_excl_scan_256(a2 + b2, t, tmp);
    if (c0 < NBKT2) Bbase[c0] = (s2 + 7) & ~7;
    if (c1 < NBKT2) Bbase[c1] = (s2 + a2 + 7) & ~7;
}

__global__ __launch_bounds__(256) void p1_kernel(const int* __restrict__ src,
                                                 const int* __restrict__ dst,
                                                 const int* __restrict__ Abase,
                                                 const int* __restrict__ hblk,
                                                 int* __restrict__ edgesA) {
    __shared__ int h[NBKT2], start[NBKT2], curb[NBKT2], resv[NBKT2], tmp[4];
    __shared__ int sortedv[BCH];
    __shared__ unsigned short sortedb[BCH];
    int tid = threadIdx.x;
    int e0 = blockIdx.x * BCH;
    int nloc = min(BCH, N_EDGES - e0);
    for (int i = tid; i < NBKT2; i += 256) h[i] = 0;
    __syncthreads();
    int myc[16], myv[16];
    const int4* __restrict__ src4 = reinterpret_cast<const int4*>(src + e0);
    const int4* __restrict__ dst4 = reinterpret_cast<const int4*>(dst + e0);
    const int n4l = nloc >> 2;
#pragma unroll
    for (int k4 = 0; k4 < 4; ++k4) {
        int i4 = k4 * 256 + tid;
        if (i4 < n4l) {
            int4 d = dst4[i4];
            int4 s = src4[i4];
            myc[k4 * 4 + 0] = d.x >> 8; myv[k4 * 4 + 0] = ((d.x & 255) << 17) | s.x;
            myc[k4 * 4 + 1] = d.y >> 8; myv[k4 * 4 + 1] = ((d.y & 255) << 17) | s.y;
            myc[k4 * 4 + 2] = d.z >> 8; myv[k4 * 4 + 2] = ((d.z & 255) << 17) | s.z;
            myc[k4 * 4 + 3] = d.w >> 8; myv[k4 * 4 + 3] = ((d.w & 255) << 17) | s.w;
            atomicAdd(&h[myc[k4 * 4 + 0]], 1);
            atomicAdd(&h[myc[k4 * 4 + 1]], 1);
            atomicAdd(&h[myc[k4 * 4 + 2]], 1);
            atomicAdd(&h[myc[k4 * 4 + 3]], 1);
        } else {
#pragma unroll
            for (int j = 0; j < 4; ++j) myc[k4 * 4 + j] = -1;
        }
    }
    __syncthreads();
    {   // scan h -> start (2 elems/thread over 512 slots)
        int a = (2 * tid < NBKT2) ? h[2 * tid] : 0;
        int b = (2 * tid + 1 < NBKT2) ? h[2 * tid + 1] : 0;
        int s = blk_excl_scan_256(a + b, tid, tmp);
        if (2 * tid < NBKT2) start[2 * tid] = s;
        if (2 * tid + 1 < NBKT2) start[2 * tid + 1] = s + a;
    }
    __syncthreads();
    for (int i = tid; i < NBKT2; i += 256) curb[i] = start[i];
    __syncthreads();
#pragma unroll
    for (int k = 0; k < 16; ++k) if (myc[k] >= 0) {
        int r = atomicAdd(&curb[myc[k]], 1);
        sortedv[r] = myv[k];
        sortedb[r] = (unsigned short)myc[k];
    }
    __syncthreads();
    // reservation = precomputed block-prefix (colscan) -- no global atomics
    for (int i = tid; i < NBKT2; i += 256) resv[i] = hblk[(size_t)blockIdx.x * NBKT2 + i];
    __syncthreads();
    for (int i = tid; i < nloc; i += 256) {                  // coalesced run writes
        int c = sortedb[i];
        edgesA[Abase[c] + resv[c] + (i - start[c])] = sortedv[i];
    }
}

// one block per bucket: count -> 8-padded scan -> private-region scatter + pads,
// emits per-8-node-group [start,end) directly (rpS / wend8)
__global__ __launch_bounds__(256) void p2_kernel(const int* __restrict__ gsize,
                                                 const int* __restrict__ Abase,
                                                 const int* __restrict__ Bbase,
                                                 const int* __restrict__ edgesA,
                                                 int* __restrict__ edgesB,
                                                 int* __restrict__ rpS,
                                                 int* __restrict__ wend8) {
    __shared__ int cnt[256], off[256], pend[256], curx[256], tmp[4];
    int b = blockIdx.x, tid = threadIdx.x;
    int nb0 = b * 256;
    int nn = min(256, N_NODES - nb0);
    int ne = gsize[b];
    int abase = Abase[b], bbase = Bbase[b];
    cnt[tid] = 0;
    __syncthreads();
    for (int i = tid; i < ne; i += 256) atomicAdd(&cnt[edgesA[abase + i] >> 17], 1);
    __syncthreads();
    int c = cnt[tid];
    int c8 = (tid < nn) ? ((c + 7) & ~7) : 0;
    int o = blk_excl_scan_256(c8, tid, tmp);
    off[tid] = o; pend[tid] = o + c8; curx[tid] = bbase + o;
    __syncthreads();
    int gc = nn >> 3;
    if (tid < gc) {
        rpS[(nb0 >> 3) + tid] = bbase + off[tid * 8];
        wend8[(nb0 >> 3) + tid] = bbase + pend[tid * 8 + 7];
    }
    for (int i = tid; i < ne; i += 256) {
        int p = edgesA[abase + i];
        int dl = p >> 17;
        int pos = atomicAdd(&curx[dl], 1);
        edgesB[pos] = ((dl & 7) << 17) | (p & 0x1FFFF);   // wave-local row | src
    }
    __syncthreads();
    if (tid < nn) {   // sentinel pads
        int pe = bbase + pend[tid];
        int sent = ((tid & 7) << 17) | SENTSRC;
        for (int pos = curx[tid]; pos < pe; ++pos) edgesB[pos] = sent;
    }
}

// ---------------- fused GraphConv layer: bf16-only h (fp32 compute) ----------
// R7-proven Phase A (word lead 6 / gather lead 3 -- depth search concluded).
// R11 hoist: Phase B operands loaded before Phase A. R13: edge-word loads are
// NONTEMPORAL (stream-once data; keeps L2 for the h gather buffer which has
// ~10x reuse at 12.8MB vs 4MB/XCD L2).
template <bool LAST>
__global__ __launch_bounds__(BLOCK) void layer_kernel(
    const ushort8_t* __restrict__ hbf_in, ushort8_t* __restrict__ hbf_out,
    const unsigned short* __restrict__ wT, const float* __restrict__ brel,
    const int* __restrict__ rpS, const int* __restrict__ wend8,
    const int* __restrict__ edges8,
    const int* __restrict__ batch, float* __restrict__ g) {
    __shared__ float agg_s[BN * SA];   // 16.6 KB
    const int tid = threadIdx.x;
    const int lane = tid & 63;
    const int wave = __builtin_amdgcn_readfirstlane(tid >> 6);
    const int node0 = blockIdx.x * BN;
    const int nvalid = min(BN, N_NODES - node0);

#pragma unroll
    for (int r = 0; r < RPW; ++r) agg_s[(wave * RPW + r) * SA + lane] = 0.f;

    // hoisted Phase-B operands (independent of Phase A)
    const int ml = lane & 15;
    const int kq = lane >> 4;               // 0..3: k-subchunk
    const int mrow = wave * 16 + ml;        // A-operand row (node_local)
    const int nrow = min(node0 + mrow, N_NODES - 1);
    bfu af2, af3;
    af2.u = hbf_in[(size_t)nrow * 8 + kq];
    af3.u = hbf_in[(size_t)nrow * 8 + 4 + kq];
    float brv[4];
#pragma unroll
    for (int nt = 0; nt < 4; ++nt) brv[nt] = brel[nt * 16 + ml];

    // Phase A: one merged 16-row run per wave, lane=dim streaming, ring pipeline
    {
        const int gg = blockIdx.x * 8 + wave * 2;   // even; gg+1 in same bucket
        if (gg < NGRP) {
            const int eb    = rpS[gg];
            const int mid   = rpS[gg + 1];
            const int end   = wend8[gg + 1];
            const int nch   = (end - eb) >> 3;      // 8-edge chunks, each = one row
            const int midch = (mid - eb) >> 3;      // chunks >= midch -> rows 8..15
            const int m = lane & 15;                // this lane's dim quad: m*4..m*4+3
            const int q = lane >> 4;                // 0..3: handles edges q and q+4
            const ushort4_t* __restrict__ h4 = (const ushort4_t*)hbf_in;
            const int rbase = wave * RPW;

            float a0 = 0.f, a1 = 0.f, a2 = 0.f, a3 = 0.f;
            int cur = -1;

#define FLUSHROW(ROW) { \
    float f0 = a0, f1 = a1, f2 = a2, f3 = a3; \
    f0 += __shfl_xor(f0, 16, 64); f1 += __shfl_xor(f1, 16, 64); \
    f2 += __shfl_xor(f2, 16, 64); f3 += __shfl_xor(f3, 16, 64); \
    f0 += __shfl_xor(f0, 32, 64); f1 += __shfl_xor(f1, 32, 64); \
    f2 += __shfl_xor(f2, 32, 64); f3 += __shfl_xor(f3, 32, 64); \
    if (lane < 16) { \
        float* p = &agg_s[(rbase + (ROW)) * SA + m * 4]; \
        p[0] = f0; p[1] = f1; p[2] = f2; p[3] = f3; } }

// per-lane NONTEMPORAL vector loads of the 2 edge words this lane consumes
#define LDW(WA, WB, CC) { \
    WA = __builtin_nontemporal_load(&edges8[eb + min((CC) * 8 + q,     lmax)]); \
    WB = __builtin_nontemporal_load(&edges8[eb + min((CC) * 8 + q + 4, lmax)]); }
// coalesced 8B gather of this lane's dim quad from rows WA, WB
#define GTH(VA_, VB_, WA, WB) { \
    VA_ = h4[(unsigned)(((WA) & 0x1FFFF) * 16 + m)]; \
    VB_ = h4[(unsigned)(((WB) & 0x1FFFF) * 16 + m)]; }

#define ACCV(VA_, VB_) { \
    a0 += b2f(VA_[0]); a1 += b2f(VA_[1]); a2 += b2f(VA_[2]); a3 += b2f(VA_[3]); \
    a0 += b2f(VB_[0]); a1 += b2f(VB_[1]); a2 += b2f(VB_[2]); a3 += b2f(VB_[3]); }

// one pipeline step: U_ static (ring indices compile-time), CC_ = chunk id
#define STEP(U_, CC_) { \
    LDW(wA[((U_) + 6) & 7], wB[((U_) + 6) & 7], (CC_) + 6) \
    GTH(VA[((U_) + 3) & 3], VB[((U_) + 3) & 3], wA[((U_) + 3) & 7], wB[((U_) + 3) & 7]) \
    const int row_ = (__builtin_amdgcn_readfirstlane(wA[(U_) & 7]) >> 17) \
                     + (((CC_) >= midch) ? 8 : 0); \
    if (row_ != cur) { \
        if (cur >= 0) FLUSHROW(cur) \
        cur = row_; \
        a0 = a1 = a2 = a3 = 0.f; \
    } \
    ACCV(VA[(U_) & 3], VB[(U_) & 3]) }

            if (nch > 0) {
                const int lmax = nch * 8 - 1;
                int wA[8], wB[8];            // ring: words of chunk c in slot c&7
                ushort4_t VA[4], VB[4];      // ring: gathered rows, slot c&3

                // prologue: words for chunks 0..5, gathers for chunks 0..2
#pragma unroll
                for (int p = 0; p < 6; ++p) LDW(wA[p], wB[p], p)
#pragma unroll
                for (int p = 0; p < 3; ++p) GTH(VA[p], VB[p], wA[p], wB[p])

                int c = 0;
                for (; c + 8 <= nch; c += 8) {   // main: static ring indices
#pragma unroll
                    for (int u = 0; u < 8; ++u) STEP(u, c + u)
                }
                if (c < nch) {                   // tail: guarded, still static
#pragma unroll
                    for (int u = 0; u < 8; ++u) {
                        if (c + u < nch) STEP(u, c + u)
                    }
                }
                if (cur >= 0) FLUSHROW(cur)
            }
#undef STEP
#undef ACCV
#undef LDW
#undef GTH
#undef FLUSHROW
        }
    }
    __syncthreads();

    // Phase B (MFMA): per wave, M-tile rows [wave*16,+16), all 4 N-tiles, K=128
    {
        bfu af[4];
        // kb 0,1: AGG (fp32 LDS -> bf16)
#pragma unroll
        for (int kb = 0; kb < 2; ++kb) {
            const float* ap = &agg_s[mrow * SA + kb * 32 + kq * 8];
#pragma unroll
            for (int j = 0; j < 8; ++j) af[kb].u[j] = f2b(ap[j]);
        }
        // kb 2,3: X own row (hoisted loads)
        af[2] = af2;
        af[3] = af3;

        f32x4v acc[4];
#pragma unroll
        for (int nt = 0; nt < 4; ++nt) {
            float bv = brv[nt];                 // D col = lane&15
            acc[nt][0] = bv; acc[nt][1] = bv; acc[nt][2] = bv; acc[nt][3] = bv;
        }
#pragma unroll
        for (int nt = 0; nt < 4; ++nt) {
            const ushort8_t* wrow =
                (const ushort8_t*)(wT + (size_t)(nt * 16 + ml) * 128);
#pragma unroll
            for (int kb = 0; kb < 4; ++kb) {
                bfu bfr; bfr.u = wrow[kb * 4 + kq];
                acc[nt] = __builtin_amdgcn_mfma_f32_16x16x32_bf16(
                    af[kb].b, bfr.b, acc[nt], 0, 0, 0);
            }
        }
        __syncthreads();   // all waves done reading agg_s
#pragma unroll
        for (int nt = 0; nt < 4; ++nt)
#pragma unroll
            for (int r = 0; r < 4; ++r)
                agg_s[(wave * 16 + kq * 4 + r) * SA + nt * 16 + ml] =
                    fmaxf(acc[nt][r], 0.f);
    }
    __syncthreads();

    if (LAST) {
        // fused global_add_pool: wave 0, lane = dim; batch is sorted
        if (wave == 0) {
            float acc = 0.f;
            int cur = batch[node0];
            for (int nl = 0; nl < nvalid; ++nl) {
                int bv = batch[node0 + nl];          // wave-uniform scalar
                float v = agg_s[nl * SA + lane];
                if (bv != cur) {
                    unsafeAtomicAdd(&g[(size_t)cur * DIM + lane], acc);
                    acc = 0.f; cur = bv;
                }
                acc += v;
            }
            unsafeAtomicAdd(&g[(size_t)cur * DIM + lane], acc);
        }
    } else {
        // coalesced bf16 store only (transpose via agg_s)
        for (int i = tid; i < nvalid * 8; i += BLOCK) {
            int nl = i >> 3, c8 = i & 7;
            const float* xp = &agg_s[nl * SA + c8 * 8];
            ushort8_t b;
#pragma unroll
            for (int j = 0; j < 8; ++j) b[j] = f2b(xp[j]);
            hbf_out[(size_t)(node0 + nl) * 8 + c8] = b;
        }
    }
}

// ---------------- classifier head: one wave per graph ----------------
__global__ __launch_bounds__(256) void head_kernel(
    const float* __restrict__ g, const float* __restrict__ W1, const float* __restrict__ b1,
    const float* __restrict__ W2, const float* __restrict__ b2, float* __restrict__ y) {
    __shared__ float ts[4][DIM];
    const int wave = threadIdx.x >> 6, lane = threadIdx.x & 63;
    const int gid = blockIdx.x * 4 + wave;          // 256*4 == N_GRAPHS exactly
    const float* __restrict__ grow = g + (size_t)gid * DIM;
    float t = b1[lane];
#pragma unroll 8
    for (int k = 0; k < DIM; ++k)
        t = fmaf(grow[k], W1[k * DIM + lane], t);   // grow[k] wave-uniform -> broadcast
    ts[wave][lane] = fmaxf(t, 0.f);
    __syncthreads();
    if (lane < OUT_DIM) {
        float acc = b2[lane];
#pragma unroll 8
        for (int d = 0; d < DIM; ++d)
            acc = fmaf(ts[wave][d], W2[d * OUT_DIM + lane], acc);
        y[(size_t)gid * OUT_DIM + lane] = acc;
    }
}

extern "C" void kernel_launch(void* const* d_in, const int* in_sizes, int n_in,
                              void* d_out, int out_size, void* d_ws, size_t ws_size,
                              hipStream_t stream) {
    const float* x     = (const float*)d_in[0];
    const int*   eidx  = (const int*)d_in[1];
    const int*   batch = (const int*)d_in[2];
    const float* Wrel  = (const float*)d_in[3];
    const float* brel  = (const float*)d_in[4];
    const float* Wroot = (const float*)d_in[5];
    const float* W1    = (const float*)d_in[6];
    const float* b1    = (const float*)d_in[7];
    const float* W2    = (const float*)d_in[8];
    const float* b2    = (const float*)d_in[9];
    float* y = (float*)d_out;

    char* ws = (char*)d_ws;
    const size_t BFBYTES = (size_t)(N_NODES + 1) * DIM * sizeof(unsigned short); // 12.8 MB + zero row
    size_t off = 0;
    ushort4* bf0 = (ushort4*)(ws + off); off += (BFBYTES + 255) / 256 * 256;
    ushort4* bf1 = (ushort4*)(ws + off); off += (BFBYTES + 255) / 256 * 256;
    int* rpS    = (int*)(ws + off); off += (size_t)NGRP * 4;
    int* wend8  = (int*)(ws + off); off += (size_t)NGRP * 4;
    int* gsize  = (int*)(ws + off); off += (size_t)NBKT2 * 4;
    int* Abase  = (int*)(ws + off); off += (size_t)NBKT2 * 4;
    int* Bbase  = (int*)(ws + off); off += (size_t)NBKT2 * 4;
    int* hblk   = (int*)(ws + off); off += (size_t)NBLK1 * NBKT2 * 4;  // 383 KB
    int* edgesA = (int*)(ws + off); off += (size_t)N_EDGES * 4;
    int* edgesB = (int*)(ws + off); off += (size_t)EPB * 4;
    float* g    = (float*)(ws + off); off += (size_t)N_GRAPHS * DIM * 4;
    unsigned short* wT = (unsigned short*)(ws + off);
    off += (size_t)NLAYERS * DIM * 2 * DIM * sizeof(unsigned short);   // 64 KB

    const int* src = eidx;
    const int* dst = eidx + N_EDGES;

    // CSR build: prep -> parallel column scan -> tiny total scan -> p1 -> p2
    prep_kernel<<<NBLK1, 256, 0, stream>>>(dst, hblk, (const float4*)x, bf0, bf1, g,
                                           Wrel, Wroot, wT);
    colscan_kernel<<<NBKT2, 256, 0, stream>>>(hblk, gsize);
    scanb2_kernel<<<1, 256, 0, stream>>>(gsize, Abase, Bbase);
    p1_kernel<<<NBLK1, 256, 0, stream>>>(src, dst, Abase, hblk, edgesA);
    p2_kernel<<<NBKT2, 256, 0, stream>>>(gsize, Abase, Bbase, edgesA, edgesB, rpS, wend8);

    // 4 GraphConv layers, bf16 ping-pong; last fuses pool
    layer_kernel<false><<<NB, BLOCK, 0, stream>>>((const ushort8_t*)bf0, (ushort8_t*)bf1,
        wT + 0 * DIM * 2 * DIM, brel + 0 * DIM, rpS, wend8, edgesB, batch, g);
    layer_kernel<false><<<NB, BLOCK, 0, stream>>>((const ushort8_t*)bf1, (ushort8_t*)bf0,
        wT + 1 * DIM * 2 * DIM, brel + 1 * DIM, rpS, wend8, edgesB, batch, g);
    layer_kernel<false><<<NB, BLOCK, 0, stream>>>((const ushort8_t*)bf0, (ushort8_t*)bf1,
        wT + 2 * DIM * 2 * DIM, brel + 2 * DIM, rpS, wend8, edgesB, batch, g);
    layer_kernel<true><<<NB, BLOCK, 0, stream>>>((const ushort8_t*)bf1, (ushort8_t*)bf0,
        wT + 3 * DIM * 2 * DIM, brel + 3 * DIM, rpS, wend8, edgesB, batch, g);

    // head
    head_kernel<<<N_GRAPHS / 4, 256, 0, stream>>>(g, W1, b1, W2, b2, y);
}

// Round 14
// 262.233 us; speedup vs baseline: 1.8419x; 1.0350x over previous
//
#include <hip/hip_runtime.h>

#define N_NODES 100000
#define N_EDGES 1000000
#define DIM 64
#define N_GRAPHS 1024
#define OUT_DIM 16
#define NLAYERS 4

#define BN 64        // nodes per block in layer kernel
#define NB 1563      // ceil(N_NODES/BN)
#define BLOCK 256    // 4 waves
#define NWAVES 4
#define RPW 16       // rows per wave = 2 merged 8-row groups
#define SA 65        // LDS row stride: 65%32==1 -> conflict-free column access
#define NGRP 12500   // N_NODES/8 wave-groups

// ---- bucket sort params ----
#define NBKT2 391            // ceil(N_NODES/256) buckets of 256 dst nodes
#define BCH 4096             // edges per pass-1 block
#define NBLK1 245            // ceil(N_EDGES/BCH)
#define SLACK 1800           // per-bucket region slack: 256*7 pad + 8 (align eats <=7)
#define EPB (N_EDGES + NBKT2 * SLACK)
#define SENTSRC N_NODES      // sentinel src -> zero bf16 row

typedef unsigned short ushort8_t __attribute__((ext_vector_type(8)));
typedef unsigned short ushort4_t __attribute__((ext_vector_type(4)));
typedef __bf16 bf16x8v __attribute__((ext_vector_type(8)));
typedef float f32x4v __attribute__((ext_vector_type(4)));

union bfu { ushort8_t u; bf16x8v b; };

__device__ __forceinline__ float b2f(unsigned short u) {
    union { unsigned int i; float f; } c;
    c.i = ((unsigned int)u) << 16;
    return c.f;
}
__device__ __forceinline__ unsigned short f2b(float f) {  // RNE
    union { float f; unsigned int i; } c;
    c.f = f;
    return (unsigned short)((c.i + 0x7FFFu + ((c.i >> 16) & 1u)) >> 16);
}

// block-wide exclusive scan of one int per thread (256 threads); tmp = 4+ ints LDS
__device__ __forceinline__ int blk_excl_scan_256(int v, int tid, int* tmp) {
    int lane = tid & 63, w = tid >> 6;
    int inc = v;
#pragma unroll
    for (int o = 1; o < 64; o <<= 1) { int u = __shfl_up(inc, o, 64); if (lane >= o) inc += u; }
    __syncthreads();              // protect tmp from any previous use
    if (lane == 63) tmp[w] = inc;
    __syncthreads();
    if (tid == 0) { int r = 0; for (int i = 0; i < 4; ++i) { int t2 = tmp[i]; tmp[i] = r; r += t2; } }
    __syncthreads();
    return inc - v + tmp[w];
}

// ---------------- prep: per-block histogram + tobf + zero g + sentinels + wT ----------------
// R10-proven structure (store counts, colscan later -- NO global atomics: R8/R9
// cost 11us; NO cooperative fusion: R12 grid.sync cost ~30-40us each).
__global__ __launch_bounds__(256) void prep_kernel(const int* __restrict__ dst,
                                                   int* __restrict__ hblk,
                                                   const float4* __restrict__ x,
                                                   ushort4* __restrict__ bf0,
                                                   ushort4* __restrict__ bf1,
                                                   float* __restrict__ g,
                                                   const float* __restrict__ Wrel,
                                                   const float* __restrict__ Wroot,
                                                   unsigned short* __restrict__ wT) {
    __shared__ int h[NBKT2];
    int tid = threadIdx.x;
    for (int i = tid; i < NBKT2; i += 256) h[i] = 0;
    __syncthreads();
    int e0 = blockIdx.x * BCH;
    int nloc = min(BCH, N_EDGES - e0);          // 4096 or 576: both /4
    const int4* __restrict__ dst4 = reinterpret_cast<const int4*>(dst + e0);
    int n4l = nloc >> 2;
    for (int i = tid; i < n4l; i += 256) {
        int4 d4 = dst4[i];
        atomicAdd(&h[d4.x >> 8], 1); atomicAdd(&h[d4.y >> 8], 1);
        atomicAdd(&h[d4.z >> 8], 1); atomicAdd(&h[d4.w >> 8], 1);
    }

    // tobf (independent)
    const int n4 = N_NODES * (DIM / 4);
    for (int i = blockIdx.x * 256 + tid; i < n4; i += NBLK1 * 256) {
        float4 v = x[i];
        ushort4 b;
        b.x = f2b(v.x); b.y = f2b(v.y); b.z = f2b(v.z); b.w = f2b(v.w);
        bf0[i] = b;
    }
    // zero g (independent; pool is fused into last layer)
    const int g4 = N_GRAPHS * (DIM / 4);
    float4 z4 = make_float4(0.f, 0.f, 0.f, 0.f);
    for (int i = blockIdx.x * 256 + tid; i < g4; i += NBLK1 * 256)
        reinterpret_cast<float4*>(g)[i] = z4;
    // transposed bf16 weight concat: wT[((l*64+n)*128)+k], k<64: Wrel[k][n], else Wroot[k-64][n]
    const int wtot = NLAYERS * DIM * 2 * DIM;   // 32768
    for (int i = blockIdx.x * 256 + tid; i < wtot; i += NBLK1 * 256) {
        int k = i & 127, n = (i >> 7) & 63, l = i >> 13;
        float v = (k < DIM) ? Wrel[l * DIM * DIM + k * DIM + n]
                            : Wroot[l * DIM * DIM + (k - DIM) * DIM + n];
        wT[i] = f2b(v);
    }
    // zero sentinel rows of both bf buffers
    if (blockIdx.x == 0 && tid < 32) {
        ushort4 z; z.x = 0; z.y = 0; z.z = 0; z.w = 0;
        if (tid < 16) bf0[(size_t)N_NODES * 16 + tid] = z;
        else          bf1[(size_t)N_NODES * 16 + (tid - 16)] = z;
    }
    __syncthreads();
    for (int i = tid; i < NBKT2; i += 256) hblk[(size_t)blockIdx.x * NBKT2 + i] = h[i];
}

// ---- column scan: one block per bucket, scan the 245 per-block counts ----
__global__ __launch_bounds__(256) void colscan_kernel(int* __restrict__ hblk,
                                                      int* __restrict__ gsize) {
    __shared__ int tmp[4];
    int c = blockIdx.x, t = threadIdx.x;
    int i0 = 2 * t, i1 = 2 * t + 1;
    int a = (i0 < NBLK1) ? hblk[(size_t)i0 * NBKT2 + c] : 0;
    int b = (i1 < NBLK1) ? hblk[(size_t)i1 * NBKT2 + c] : 0;
    int s = blk_excl_scan_256(a + b, t, tmp);
    if (i0 < NBLK1) hblk[(size_t)i0 * NBKT2 + c] = s;
    if (i1 < NBLK1) hblk[(size_t)i1 * NBKT2 + c] = s + a;
    if (t == 255) gsize[c] = s + a + b;   // column total
}

// tiny single block: scan 391 bucket totals -> Abase, Bbase
// Bbase rounded up to x8 ints (32B): every row-run chunk of 8 edges is then
// 32B-aligned (p2 pads runs to x8) -> chunk c of a run is one dst row.
__global__ __launch_bounds__(256) void scanb2_kernel(const int* __restrict__ gsize,
                                                     int* __restrict__ Abase,
                                                     int* __restrict__ Bbase) {
    __shared__ int tmp[4];
    int t = threadIdx.x;
    int c0 = 2 * t, c1 = 2 * t + 1;
    int a = (c0 < NBKT2) ? gsize[c0] : 0;
    int b = (c1 < NBKT2) ? gsize[c1] : 0;
    int s = blk_excl_scan_256(a + b, t, tmp);
    if (c0 < NBKT2) Abase[c0] = s;
    if (c1 < NBKT2) Abase[c1] = s + a;
    int a2 = (c0 < NBKT2) ? a + SLACK : 0;
    int b2 = (c1 < NBKT2) ? b + SLACK : 0;
    int s2 = blk_excl_scan_256(a2 + b2, t, tmp);
    if (c0 < NBKT2) Bbase[c0] = (s2 + 7) & ~7;
    if (c1 < NBKT2) Bbase[c1] = (s2 + a2 + 7) & ~7;
}

__global__ __launch_bounds__(256) void p1_kernel(const int* __restrict__ src,
                                                 const int* __restrict__ dst,
                                                 const int* __restrict__ Abase,
                                                 const int* __restrict__ hblk,
                                                 int* __restrict__ edgesA) {
    __shared__ int h[NBKT2], start[NBKT2], curb[NBKT2], resv[NBKT2], tmp[4];
    __shared__ int sortedv[BCH];
    __shared__ unsigned short sortedb[BCH];
    int tid = threadIdx.x;
    int e0 = blockIdx.x * BCH;
    int nloc = min(BCH, N_EDGES - e0);
    for (int i = tid; i < NBKT2; i += 256) h[i] = 0;
    __syncthreads();
    int myc[16], myv[16];
    const int4* __restrict__ src4 = reinterpret_cast<const int4*>(src + e0);
    const int4* __restrict__ dst4 = reinterpret_cast<const int4*>(dst + e0);
    const int n4l = nloc >> 2;
#pragma unroll
    for (int k4 = 0; k4 < 4; ++k4) {
        int i4 = k4 * 256 + tid;
        if (i4 < n4l) {
            int4 d = dst4[i4];
            int4 s = src4[i4];
            myc[k4 * 4 + 0] = d.x >> 8; myv[k4 * 4 + 0] = ((d.x & 255) << 17) | s.x;
            myc[k4 * 4 + 1] = d.y >> 8; myv[k4 * 4 + 1] = ((d.y & 255) << 17) | s.y;
            myc[k4 * 4 + 2] = d.z >> 8; myv[k4 * 4 + 2] = ((d.z & 255) << 17) | s.z;
            myc[k4 * 4 + 3] = d.w >> 8; myv[k4 * 4 + 3] = ((d.w & 255) << 17) | s.w;
            atomicAdd(&h[myc[k4 * 4 + 0]], 1);
            atomicAdd(&h[myc[k4 * 4 + 1]], 1);
            atomicAdd(&h[myc[k4 * 4 + 2]], 1);
            atomicAdd(&h[myc[k4 * 4 + 3]], 1);
        } else {
#pragma unroll
            for (int j = 0; j < 4; ++j) myc[k4 * 4 + j] = -1;
        }
    }
    __syncthreads();
    {   // scan h -> start (2 elems/thread over 512 slots)
        int a = (2 * tid < NBKT2) ? h[2 * tid] : 0;
        int b = (2 * tid + 1 < NBKT2) ? h[2 * tid + 1] : 0;
        int s = blk_excl_scan_256(a + b, tid, tmp);
        if (2 * tid < NBKT2) start[2 * tid] = s;
        if (2 * tid + 1 < NBKT2) start[2 * tid + 1] = s + a;
    }
    __syncthreads();
    for (int i = tid; i < NBKT2; i += 256) curb[i] = start[i];
    __syncthreads();
#pragma unroll
    for (int k = 0; k < 16; ++k) if (myc[k] >= 0) {
        int r = atomicAdd(&curb[myc[k]], 1);
        sortedv[r] = myv[k];
        sortedb[r] = (unsigned short)myc[k];
    }
    __syncthreads();
    // reservation = precomputed block-prefix (colscan) -- no global atomics
    for (int i = tid; i < NBKT2; i += 256) resv[i] = hblk[(size_t)blockIdx.x * NBKT2 + i];
    __syncthreads();
    for (int i = tid; i < nloc; i += 256) {                  // coalesced run writes
        int c = sortedb[i];
        edgesA[Abase[c] + resv[c] + (i - start[c])] = sortedv[i];
    }
}

// one block per bucket: count -> 8-padded scan -> private-region scatter + pads,
// emits per-8-node-group [start,end) directly (rpS / wend8)
__global__ __launch_bounds__(256) void p2_kernel(const int* __restrict__ gsize,
                                                 const int* __restrict__ Abase,
                                                 const int* __restrict__ Bbase,
                                                 const int* __restrict__ edgesA,
                                                 int* __restrict__ edgesB,
                                                 int* __restrict__ rpS,
                                                 int* __restrict__ wend8) {
    __shared__ int cnt[256], off[256], pend[256], curx[256], tmp[4];
    int b = blockIdx.x, tid = threadIdx.x;
    int nb0 = b * 256;
    int nn = min(256, N_NODES - nb0);
    int ne = gsize[b];
    int abase = Abase[b], bbase = Bbase[b];
    cnt[tid] = 0;
    __syncthreads();
    for (int i = tid; i < ne; i += 256) atomicAdd(&cnt[edgesA[abase + i] >> 17], 1);
    __syncthreads();
    int c = cnt[tid];
    int c8 = (tid < nn) ? ((c + 7) & ~7) : 0;
    int o = blk_excl_scan_256(c8, tid, tmp);
    off[tid] = o; pend[tid] = o + c8; curx[tid] = bbase + o;
    __syncthreads();
    int gc = nn >> 3;
    if (tid < gc) {
        rpS[(nb0 >> 3) + tid] = bbase + off[tid * 8];
        wend8[(nb0 >> 3) + tid] = bbase + pend[tid * 8 + 7];
    }
    for (int i = tid; i < ne; i += 256) {
        int p = edgesA[abase + i];
        int dl = p >> 17;
        int pos = atomicAdd(&curx[dl], 1);
        edgesB[pos] = ((dl & 7) << 17) | (p & 0x1FFFF);   // wave-local row | src
    }
    __syncthreads();
    if (tid < nn) {   // sentinel pads
        int pe = bbase + pend[tid];
        int sent = ((tid & 7) << 17) | SENTSRC;
        for (int pos = curx[tid]; pos < pe; ++pos) edgesB[pos] = sent;
    }
}

// ---------------- fused GraphConv layer: bf16-only h (fp32 compute) ----------
// R7-proven Phase A (word lead 6 / gather lead 3 -- depth search concluded).
// R11 hoist: Phase B operands loaded before Phase A. R14: nontemporal hint
// REVERTED (R13: +4.5us -- edge stream was L2-warm from p2's writes; nt
// turned warm hits into HBM fetches).
template <bool LAST>
__global__ __launch_bounds__(BLOCK) void layer_kernel(
    const ushort8_t* __restrict__ hbf_in, ushort8_t* __restrict__ hbf_out,
    const unsigned short* __restrict__ wT, const float* __restrict__ brel,
    const int* __restrict__ rpS, const int* __restrict__ wend8,
    const int* __restrict__ edges8,
    const int* __restrict__ batch, float* __restrict__ g) {
    __shared__ float agg_s[BN * SA];   // 16.6 KB
    const int tid = threadIdx.x;
    const int lane = tid & 63;
    const int wave = __builtin_amdgcn_readfirstlane(tid >> 6);
    const int node0 = blockIdx.x * BN;
    const int nvalid = min(BN, N_NODES - node0);

#pragma unroll
    for (int r = 0; r < RPW; ++r) agg_s[(wave * RPW + r) * SA + lane] = 0.f;

    // hoisted Phase-B operands (independent of Phase A)
    const int ml = lane & 15;
    const int kq = lane >> 4;               // 0..3: k-subchunk
    const int mrow = wave * 16 + ml;        // A-operand row (node_local)
    const int nrow = min(node0 + mrow, N_NODES - 1);
    bfu af2, af3;
    af2.u = hbf_in[(size_t)nrow * 8 + kq];
    af3.u = hbf_in[(size_t)nrow * 8 + 4 + kq];
    float brv[4];
#pragma unroll
    for (int nt = 0; nt < 4; ++nt) brv[nt] = brel[nt * 16 + ml];

    // Phase A: one merged 16-row run per wave, lane=dim streaming, ring pipeline
    {
        const int gg = blockIdx.x * 8 + wave * 2;   // even; gg+1 in same bucket
        if (gg < NGRP) {
            const int eb    = rpS[gg];
            const int mid   = rpS[gg + 1];
            const int end   = wend8[gg + 1];
            const int nch   = (end - eb) >> 3;      // 8-edge chunks, each = one row
            const int midch = (mid - eb) >> 3;      // chunks >= midch -> rows 8..15
            const int m = lane & 15;                // this lane's dim quad: m*4..m*4+3
            const int q = lane >> 4;                // 0..3: handles edges q and q+4
            const ushort4_t* __restrict__ h4 = (const ushort4_t*)hbf_in;
            const int rbase = wave * RPW;

            float a0 = 0.f, a1 = 0.f, a2 = 0.f, a3 = 0.f;
            int cur = -1;

#define FLUSHROW(ROW) { \
    float f0 = a0, f1 = a1, f2 = a2, f3 = a3; \
    f0 += __shfl_xor(f0, 16, 64); f1 += __shfl_xor(f1, 16, 64); \
    f2 += __shfl_xor(f2, 16, 64); f3 += __shfl_xor(f3, 16, 64); \
    f0 += __shfl_xor(f0, 32, 64); f1 += __shfl_xor(f1, 32, 64); \
    f2 += __shfl_xor(f2, 32, 64); f3 += __shfl_xor(f3, 32, 64); \
    if (lane < 16) { \
        float* p = &agg_s[(rbase + (ROW)) * SA + m * 4]; \
        p[0] = f0; p[1] = f1; p[2] = f2; p[3] = f3; } }

// per-lane vector loads of the 2 edge words this lane consumes (vmcnt-counted)
#define LDW(WA, WB, CC) { \
    WA = edges8[eb + min((CC) * 8 + q,     lmax)]; \
    WB = edges8[eb + min((CC) * 8 + q + 4, lmax)]; }
// coalesced 8B gather of this lane's dim quad from rows WA, WB
#define GTH(VA_, VB_, WA, WB) { \
    VA_ = h4[(unsigned)(((WA) & 0x1FFFF) * 16 + m)]; \
    VB_ = h4[(unsigned)(((WB) & 0x1FFFF) * 16 + m)]; }

#define ACCV(VA_, VB_) { \
    a0 += b2f(VA_[0]); a1 += b2f(VA_[1]); a2 += b2f(VA_[2]); a3 += b2f(VA_[3]); \
    a0 += b2f(VB_[0]); a1 += b2f(VB_[1]); a2 += b2f(VB_[2]); a3 += b2f(VB_[3]); }

// one pipeline step: U_ static (ring indices compile-time), CC_ = chunk id
#define STEP(U_, CC_) { \
    LDW(wA[((U_) + 6) & 7], wB[((U_) + 6) & 7], (CC_) + 6) \
    GTH(VA[((U_) + 3) & 3], VB[((U_) + 3) & 3], wA[((U_) + 3) & 7], wB[((U_) + 3) & 7]) \
    const int row_ = (__builtin_amdgcn_readfirstlane(wA[(U_) & 7]) >> 17) \
                     + (((CC_) >= midch) ? 8 : 0); \
    if (row_ != cur) { \
        if (cur >= 0) FLUSHROW(cur) \
        cur = row_; \
        a0 = a1 = a2 = a3 = 0.f; \
    } \
    ACCV(VA[(U_) & 3], VB[(U_) & 3]) }

            if (nch > 0) {
                const int lmax = nch * 8 - 1;
                int wA[8], wB[8];            // ring: words of chunk c in slot c&7
                ushort4_t VA[4], VB[4];      // ring: gathered rows, slot c&3

                // prologue: words for chunks 0..5, gathers for chunks 0..2
#pragma unroll
                for (int p = 0; p < 6; ++p) LDW(wA[p], wB[p], p)
#pragma unroll
                for (int p = 0; p < 3; ++p) GTH(VA[p], VB[p], wA[p], wB[p])

                int c = 0;
                for (; c + 8 <= nch; c += 8) {   // main: static ring indices
#pragma unroll
                    for (int u = 0; u < 8; ++u) STEP(u, c + u)
                }
                if (c < nch) {                   // tail: guarded, still static
#pragma unroll
                    for (int u = 0; u < 8; ++u) {
                        if (c + u < nch) STEP(u, c + u)
                    }
                }
                if (cur >= 0) FLUSHROW(cur)
            }
#undef STEP
#undef ACCV
#undef LDW
#undef GTH
#undef FLUSHROW
        }
    }
    __syncthreads();

    // Phase B (MFMA): per wave, M-tile rows [wave*16,+16), all 4 N-tiles, K=128
    {
        bfu af[4];
        // kb 0,1: AGG (fp32 LDS -> bf16)
#pragma unroll
        for (int kb = 0; kb < 2; ++kb) {
            const float* ap = &agg_s[mrow * SA + kb * 32 + kq * 8];
#pragma unroll
            for (int j = 0; j < 8; ++j) af[kb].u[j] = f2b(ap[j]);
        }
        // kb 2,3: X own row (hoisted loads)
        af[2] = af2;
        af[3] = af3;

        f32x4v acc[4];
#pragma unroll
        for (int nt = 0; nt < 4; ++nt) {
            float bv = brv[nt];                 // D col = lane&15
            acc[nt][0] = bv; acc[nt][1] = bv; acc[nt][2] = bv; acc[nt][3] = bv;
        }
#pragma unroll
        for (int nt = 0; nt < 4; ++nt) {
            const ushort8_t* wrow =
                (const ushort8_t*)(wT + (size_t)(nt * 16 + ml) * 128);
#pragma unroll
            for (int kb = 0; kb < 4; ++kb) {
                bfu bfr; bfr.u = wrow[kb * 4 + kq];
                acc[nt] = __builtin_amdgcn_mfma_f32_16x16x32_bf16(
                    af[kb].b, bfr.b, acc[nt], 0, 0, 0);
            }
        }
        __syncthreads();   // all waves done reading agg_s
#pragma unroll
        for (int nt = 0; nt < 4; ++nt)
#pragma unroll
            for (int r = 0; r < 4; ++r)
                agg_s[(wave * 16 + kq * 4 + r) * SA + nt * 16 + ml] =
                    fmaxf(acc[nt][r], 0.f);
    }
    __syncthreads();

    if (LAST) {
        // fused global_add_pool: wave 0, lane = dim; batch is sorted
        if (wave == 0) {
            float acc = 0.f;
            int cur = batch[node0];
            for (int nl = 0; nl < nvalid; ++nl) {
                int bv = batch[node0 + nl];          // wave-uniform scalar
                float v = agg_s[nl * SA + lane];
                if (bv != cur) {
                    unsafeAtomicAdd(&g[(size_t)cur * DIM + lane], acc);
                    acc = 0.f; cur = bv;
                }
                acc += v;
            }
            unsafeAtomicAdd(&g[(size_t)cur * DIM + lane], acc);
        }
    } else {
        // coalesced bf16 store only (transpose via agg_s)
        for (int i = tid; i < nvalid * 8; i += BLOCK) {
            int nl = i >> 3, c8 = i & 7;
            const float* xp = &agg_s[nl * SA + c8 * 8];
            ushort8_t b;
#pragma unroll
            for (int j = 0; j < 8; ++j) b[j] = f2b(xp[j]);
            hbf_out[(size_t)(node0 + nl) * 8 + c8] = b;
        }
    }
}

// ---------------- classifier head: one wave per graph ----------------
__global__ __launch_bounds__(256) void head_kernel(
    const float* __restrict__ g, const float* __restrict__ W1, const float* __restrict__ b1,
    const float* __restrict__ W2, const float* __restrict__ b2, float* __restrict__ y) {
    __shared__ float ts[4][DIM];
    const int wave = threadIdx.x >> 6, lane = threadIdx.x & 63;
    const int gid = blockIdx.x * 4 + wave;          // 256*4 == N_GRAPHS exactly
    const float* __restrict__ grow = g + (size_t)gid * DIM;
    float t = b1[lane];
#pragma unroll 8
    for (int k = 0; k < DIM; ++k)
        t = fmaf(grow[k], W1[k * DIM + lane], t);   // grow[k] wave-uniform -> broadcast
    ts[wave][lane] = fmaxf(t, 0.f);
    __syncthreads();
    if (lane < OUT_DIM) {
        float acc = b2[lane];
#pragma unroll 8
        for (int d = 0; d < DIM; ++d)
            acc = fmaf(ts[wave][d], W2[d * OUT_DIM + lane], acc);
        y[(size_t)gid * OUT_DIM + lane] = acc;
    }
}

extern "C" void kernel_launch(void* const* d_in, const int* in_sizes, int n_in,
                              void* d_out, int out_size, void* d_ws, size_t ws_size,
                              hipStream_t stream) {
    const float* x     = (const float*)d_in[0];
    const int*   eidx  = (const int*)d_in[1];
    const int*   batch = (const int*)d_in[2];
    const float* Wrel  = (const float*)d_in[3];
    const float* brel  = (const float*)d_in[4];
    const float* Wroot = (const float*)d_in[5];
    const float* W1    = (const float*)d_in[6];
    const float* b1    = (const float*)d_in[7];
    const float* W2    = (const float*)d_in[8];
    const float* b2    = (const float*)d_in[9];
    float* y = (float*)d_out;

    char* ws = (char*)d_ws;
    const size_t BFBYTES = (size_t)(N_NODES + 1) * DIM * sizeof(unsigned short); // 12.8 MB + zero row
    size_t off = 0;
    ushort4* bf0 = (ushort4*)(ws + off); off += (BFBYTES + 255) / 256 * 256;
    ushort4* bf1 = (ushort4*)(ws + off); off += (BFBYTES + 255) / 256 * 256;
    int* rpS    = (int*)(ws + off); off += (size_t)NGRP * 4;
    int* wend8  = (int*)(ws + off); off += (size_t)NGRP * 4;
    int* gsize  = (int*)(ws + off); off += (size_t)NBKT2 * 4;
    int* Abase  = (int*)(ws + off); off += (size_t)NBKT2 * 4;
    int* Bbase  = (int*)(ws + off); off += (size_t)NBKT2 * 4;
    int* hblk   = (int*)(ws + off); off += (size_t)NBLK1 * NBKT2 * 4;  // 383 KB
    int* edgesA = (int*)(ws + off); off += (size_t)N_EDGES * 4;
    int* edgesB = (int*)(ws + off); off += (size_t)EPB * 4;
    float* g    = (float*)(ws + off); off += (size_t)N_GRAPHS * DIM * 4;
    unsigned short* wT = (unsigned short*)(ws + off);
    off += (size_t)NLAYERS * DIM * 2 * DIM * sizeof(unsigned short);   // 64 KB

    const int* src = eidx;
    const int* dst = eidx + N_EDGES;

    // CSR build: prep -> parallel column scan -> tiny total scan -> p1 -> p2
    prep_kernel<<<NBLK1, 256, 0, stream>>>(dst, hblk, (const float4*)x, bf0, bf1, g,
                                           Wrel, Wroot, wT);
    colscan_kernel<<<NBKT2, 256, 0, stream>>>(hblk, gsize);
    scanb2_kernel<<<1, 256, 0, stream>>>(gsize, Abase, Bbase);
    p1_kernel<<<NBLK1, 256, 0, stream>>>(src, dst, Abase, hblk, edgesA);
    p2_kernel<<<NBKT2, 256, 0, stream>>>(gsize, Abase, Bbase, edgesA, edgesB, rpS, wend8);

    // 4 GraphConv layers, bf16 ping-pong; last fuses pool
    layer_kernel<false><<<NB, BLOCK, 0, stream>>>((const ushort8_t*)bf0, (ushort8_t*)bf1,
        wT + 0 * DIM * 2 * DIM, brel + 0 * DIM, rpS, wend8, edgesB, batch, g);
    layer_kernel<false><<<NB, BLOCK, 0, stream>>>((const ushort8_t*)bf1, (ushort8_t*)bf0,
        wT + 1 * DIM * 2 * DIM, brel + 1 * DIM, rpS, wend8, edgesB, batch, g);
    layer_kernel<false><<<NB, BLOCK, 0, stream>>>((const ushort8_t*)bf0, (ushort8_t*)bf1,
        wT + 2 * DIM * 2 * DIM, brel + 2 * DIM, rpS, wend8, edgesB, batch, g);
    layer_kernel<true><<<NB, BLOCK, 0, stream>>>((const ushort8_t*)bf1, (ushort8_t*)bf0,
        wT + 3 * DIM * 2 * DIM, brel + 3 * DIM, rpS, wend8, edgesB, batch, g);

    // head
    head_kernel<<<N_GRAPHS / 4, 256, 0, stream>>>(g, W1, b1, W2, b2, y);
}